// Round 1
// baseline (1806.454 us; speedup 1.0000x reference)
//
#include <hip/hip_runtime.h>
#include <hip/hip_fp16.h>
#include <math.h>

#define ROW_FEAT 256
#define BLOCK_THREADS 1024
#define WAVES_PB (BLOCK_THREADS / 64)
#define SCRATCH_F 512

// weight offsets in halfs inside LDS
#define OFF_W1   0
#define OFF_W2   4096
#define OFF_W3   8192
#define OFF_W4   12288
#define OFF_WM1  16384
#define OFF_WM2  20480
#define OFF_WM3  24576
#define OFF_WL0  40960
#define OFF_WL1  49152
#define W_HALFS  57344

#define SMEM_BYTES (W_HALFS * 2 + WAVES_PB * SCRATCH_F * 4)  // 114688 + 32768 = 147456

__device__ __forceinline__ float h2f(__half h) { return __half2float(h); }

__global__ __launch_bounds__(BLOCK_THREADS, 1)
void tp_fused(const float* __restrict__ x, const float* __restrict__ y,
              const float* __restrict__ scalars,
              const float* __restrict__ W1, const float* __restrict__ W2,
              const float* __restrict__ W3, const float* __restrict__ W4,
              const float* __restrict__ Wm1, const float* __restrict__ Wm2,
              const float* __restrict__ Wm3, const float* __restrict__ Wl0,
              const float* __restrict__ Wl1,
              float* __restrict__ out, int nrows, float silu_cst)
{
    extern __shared__ char smem[];
    __half* wh = (__half*)smem;
    float* scratch = (float*)(smem + W_HALFS * 2);

    const int tid = threadIdx.x;

    // ---- stage all weights into LDS as fp16 (112 KB) ----
    {
        const float* srcs[9] = {W1, W2, W3, W4, Wm1, Wm2, Wm3, Wl0, Wl1};
        const int offs[9] = {OFF_W1, OFF_W2, OFF_W3, OFF_W4, OFF_WM1,
                             OFF_WM2, OFF_WM3, OFF_WL0, OFF_WL1};
        const int cnts[9] = {4096, 4096, 4096, 4096, 4096, 4096, 16384, 8192, 8192};
        for (int m = 0; m < 9; m++) {
            const float* s = srcs[m];
            __half* d = wh + offs[m];
            for (int i = tid; i < cnts[m]; i += BLOCK_THREADS) d[i] = __float2half(s[i]);
        }
    }
    __syncthreads();

    const int lane = tid & 63;
    const int wave = tid >> 6;
    float* sw   = scratch + wave * SCRATCH_F;
    float* sbuf = sw;          // 64: scalars / h1 / h2 broadcasts
    float* xbuf = sw + 64;     // 256: x row
    float* tbuf = sw + 320;    // 64: t0
    float* scb  = sw + 384;    // 128: sc0
    float* pw   = sw + 64;     // 64 (reuses xbuf after dot phase)
    float* qw0  = sw + 128;    // 64
    float* qw1  = sw + 192;    // 64
    float* qw2  = sw + 256;    // 64

    const float s1    = 0.125f;                 // 1/sqrt(64)
    const float s2c   = 0.07216878364870322f;   // 1/sqrt(192)
    const float lin_s = 0.08838834764831845f;   // 1/sqrt(128)
    const float inv8  = 0.125f;

    const int wtotal = gridDim.x * WAVES_PB;
    const int iters = (nrows + wtotal - 1) / wtotal;
    int b = blockIdx.x * WAVES_PB + wave;

    for (int it = 0; it < iters; ++it, b += wtotal) {
        const bool active = (b < nrows);
        __syncthreads();  // protect previous iteration's reads from new writes

        float y0 = 0.f, y10 = 0.f, y11 = 0.f, y12 = 0.f;
        if (active) {
            const float* xr = x + (size_t)b * ROW_FEAT;
            xbuf[lane]       = xr[lane];
            xbuf[64 + lane]  = xr[64 + lane];
            xbuf[128 + lane] = xr[128 + lane];
            xbuf[192 + lane] = xr[192 + lane];
            sbuf[lane] = scalars[(size_t)b * 64 + lane];
            y0  = y[(size_t)b * 4 + 0];
            y10 = y[(size_t)b * 4 + 1];
            y11 = y[(size_t)b * 4 + 2];
            y12 = y[(size_t)b * 4 + 3];
        }
        __syncthreads();

        // ---- MLP layer 1 + t0 = sum_i x1[u,i]*y1[i] ----
        float h1 = 0.f, t0 = 0.f;
        if (active) {
            float acc = 0.f;
            #pragma unroll 4
            for (int u = 0; u < 64; u++)
                acc += sbuf[u] * h2f(wh[OFF_WM1 + u * 64 + lane]);
            float t = acc * inv8;
            h1 = t / (1.f + __expf(-t)) * silu_cst;
            t0 = xbuf[64 + 3 * lane] * y10 + xbuf[64 + 3 * lane + 1] * y11 +
                 xbuf[64 + 3 * lane + 2] * y12;
        }
        __syncthreads();
        if (active) { sbuf[lane] = h1; tbuf[lane] = t0; }
        __syncthreads();

        // ---- MLP layer 2 ----
        float h2v = 0.f;
        if (active) {
            float acc = 0.f;
            #pragma unroll 4
            for (int u = 0; u < 64; u++)
                acc += sbuf[u] * h2f(wh[OFF_WM2 + u * 64 + lane]);
            float t = acc * inv8;
            h2v = t / (1.f + __expf(-t)) * silu_cst;
        }
        __syncthreads();
        if (active) sbuf[lane] = h2v;
        __syncthreads();

        // ---- MLP layer 3 (wts) + the 6 tensor-product contractions ----
        float sc0a = 0.f, sc0b = 0.f, pwv = 0.f, qv0 = 0.f, qv1 = 0.f, qv2 = 0.f;
        if (active) {
            float wa0 = 0.f, wa1 = 0.f, wa2 = 0.f, wa3 = 0.f;
            #pragma unroll 4
            for (int u = 0; u < 64; u++) {
                float hv = sbuf[u];
                wa0 += hv * h2f(wh[OFF_WM3 + u * 256 + lane]);
                wa1 += hv * h2f(wh[OFF_WM3 + u * 256 + 64 + lane]);
                wa2 += hv * h2f(wh[OFF_WM3 + u * 256 + 128 + lane]);
                wa3 += hv * h2f(wh[OFF_WM3 + u * 256 + 192 + lane]);
            }
            const float w0a = wa0 * inv8, w0b = wa1 * inv8;
            const float w1a = wa2 * inv8, w1b = wa3 * inv8;

            float d1 = 0.f, d2 = 0.f, pp = 0.f, q0 = 0.f, q1 = 0.f, q2 = 0.f;
            #pragma unroll 4
            for (int u = 0; u < 64; u++) {
                float xb  = xbuf[u];
                float tb  = tbuf[u];
                float xa  = xbuf[64 + 3 * u];
                float xbb = xbuf[64 + 3 * u + 1];
                float xc  = xbuf[64 + 3 * u + 2];
                float w1v = h2f(wh[OFF_W1 + u * 64 + lane]);
                float w2v = h2f(wh[OFF_W2 + u * 64 + lane]);
                float w3v = h2f(wh[OFF_W3 + u * 64 + lane]);
                float w4v = h2f(wh[OFF_W4 + u * 64 + lane]);
                d1 += xb * w1v;
                d2 += tb * w2v;
                pp += xb * w3v;
                q0 += xa * w4v;
                q1 += xbb * w4v;
                q2 += xc * w4v;
            }
            sc0a = s1 * y0 * d1 * w0a;   // out0a * w0   (y0 factored out of the GEMV)
            sc0b = s2c * d2 * w0b;       // out0b * w0
            pwv  = pp * w1a;             // p * w1 (y1[i] outer product folded later)
            qv0  = q0 * w1b;
            qv1  = q1 * w1b;
            qv2  = q2 * w1b;
        }
        __syncthreads();
        if (active) {
            scb[lane] = sc0a; scb[64 + lane] = sc0b;
            pw[lane] = pwv; qw0[lane] = qv0; qw1[lane] = qv1; qw2[lane] = qv2;
        }
        __syncthreads();

        // ---- output layer ----
        if (active) {
            float o0 = 0.f, r0 = 0.f, rq0 = 0.f, rq1 = 0.f, rq2 = 0.f;
            #pragma unroll 4
            for (int u = 0; u < 64; u++) {
                float l0a = h2f(wh[OFF_WL0 + u * 64 + lane]);
                float l0b = h2f(wh[OFF_WL0 + (64 + u) * 64 + lane]);
                float l1a = h2f(wh[OFF_WL1 + u * 64 + lane]);
                float l1b = h2f(wh[OFF_WL1 + (64 + u) * 64 + lane]);
                o0  += scb[u] * l0a + scb[64 + u] * l0b;
                r0  += pw[u] * l1a;
                rq0 += qw0[u] * l1b;
                rq1 += qw1[u] * l1b;
                rq2 += qw2[u] * l1b;
            }
            float* orow = out + (size_t)b * ROW_FEAT;
            orow[lane] = lin_s * o0;
            const float c = lin_s * s1;
            orow[64 + 3 * lane + 0] = c * (y10 * r0 + y0 * rq0);
            orow[64 + 3 * lane + 1] = c * (y11 * r0 + y0 * rq1);
            orow[64 + 3 * lane + 2] = c * (y12 * r0 + y0 * rq2);
        }
    }
}

extern "C" void kernel_launch(void* const* d_in, const int* in_sizes, int n_in,
                              void* d_out, int out_size, void* d_ws, size_t ws_size,
                              hipStream_t stream)
{
    (void)n_in; (void)d_ws; (void)ws_size; (void)out_size;
    const float* x       = (const float*)d_in[0];
    const float* y       = (const float*)d_in[1];
    const float* scalars = (const float*)d_in[2];
    const float* W1  = (const float*)d_in[3];
    const float* W2  = (const float*)d_in[4];
    const float* W3  = (const float*)d_in[5];
    const float* W4  = (const float*)d_in[6];
    const float* Wm1 = (const float*)d_in[7];
    const float* Wm2 = (const float*)d_in[8];
    const float* Wm3 = (const float*)d_in[9];
    const float* Wl0 = (const float*)d_in[10];
    const float* Wl1 = (const float*)d_in[11];
    float* out = (float*)d_out;
    const int nrows = in_sizes[0] / ROW_FEAT;

    // SILU_CST = 1/sqrt(E[silu(z)^2]), z~N(0,1). Simpson over [-13,13]
    // matches the reference's 201-pt Gauss-Hermite to ~1e-9.
    double a = -13.0, bb = 13.0;
    const int nst = 4096;
    double h = (bb - a) / nst, sum = 0.0;
    for (int i = 0; i <= nst; i++) {
        double z = a + i * h;
        double sig = 1.0 / (1.0 + exp(-z));
        double sl = z * sig;
        double f = sl * sl * exp(-0.5 * z * z);
        double w = (i == 0 || i == nst) ? 1.0 : ((i & 1) ? 4.0 : 2.0);
        sum += w * f;
    }
    sum *= h / 3.0 / sqrt(2.0 * M_PI);
    const float silu_cst = (float)(1.0 / sqrt(sum));

    hipFuncSetAttribute(reinterpret_cast<const void*>(tp_fused),
                        hipFuncAttributeMaxDynamicSharedMemorySize, SMEM_BYTES);
    tp_fused<<<256, BLOCK_THREADS, SMEM_BYTES, stream>>>(
        x, y, scalars, W1, W2, W3, W4, Wm1, Wm2, Wm3, Wl0, Wl1,
        out, nrows, silu_cst);
}